// Round 1
// 6998.261 us; speedup vs baseline: 1.0773x; 1.0773x over previous
//
#include <hip/hip_runtime.h>

typedef __attribute__((ext_vector_type(8))) short bf16x8;   // 8 bf16 (4 VGPRs)
typedef __attribute__((ext_vector_type(4))) float f32x4;
typedef unsigned short u16;
typedef unsigned long long u64;

#define T_SEQ 512
#define NBLK  192
#define FPAD  16        // ints per flag slot = one 64B line
#define RSLOT 4         // ring depth for h0ring / h1ring / pabuf

__device__ __forceinline__ u16 f2bf(float f) {
  unsigned int u = __float_as_uint(f);
  u += 0x7fffu + ((u >> 16) & 1u);           // RNE
  return (u16)(u >> 16);
}
__device__ __forceinline__ float sigm_(float x) { return 1.f / (1.f + __expf(-x)); }
__device__ __forceinline__ float tanh_(float x) { return 1.f - 2.f / (__expf(2.f * x) + 1.f); }

// agent-scope (device-coherent) access. COMPILER-VISIBLE (tracked by vmcnt
// insertion, drained before every s_barrier). No wbl2 needed.
template <typename T>
__device__ __forceinline__ void st_agent(T* p, T v) {
  __hip_atomic_store(p, v, __ATOMIC_RELAXED, __HIP_MEMORY_SCOPE_AGENT);
}
template <typename T>
__device__ __forceinline__ T ld_agent(const T* p) {
  return __hip_atomic_load(p, __ATOMIC_RELAXED, __HIP_MEMORY_SCOPE_AGENT);
}
__device__ __forceinline__ u64 pack2f(float a, float b) {
  return (u64)__float_as_uint(a) | ((u64)__float_as_uint(b) << 32);
}
__device__ __forceinline__ u64 pack4bf(f32x4 v) {
  return (u64)f2bf(v[0]) | ((u64)f2bf(v[1]) << 16) |
         ((u64)f2bf(v[2]) << 32) | ((u64)f2bf(v[3]) << 48);
}

// ---------- prologue kernels ----------
__global__ void fc_kernel(const float* __restrict__ x, const float* __restrict__ w,
                          const float* __restrict__ bias, float* __restrict__ z) {
  int idx = blockIdx.x * 256 + threadIdx.x;    // 131072 = 128*1024
  int b = idx >> 10, i = idx & 1023;
  const float* xr = x + b * 256;
  const float* wr = w + i * 256;
  float acc = bias[i];
  #pragma unroll 4
  for (int o = 0; o < 256; ++o) acc += xr[o] * wr[o];
  z[idx] = acc;
}

__global__ void gx0_kernel(const float* __restrict__ z, const float* __restrict__ Wih0,
                           const float* __restrict__ bih, const float* __restrict__ bhh,
                           float* __restrict__ gx0) {
  int idx = blockIdx.x * 256 + threadIdx.x;    // 524288 = 128*4096
  int b = idx >> 12, j = idx & 4095;
  const float* zr = z + b * 1024;
  const float* wr = Wih0 + (size_t)j * 1024;
  float acc = bih[j] + bhh[j];
  #pragma unroll 4
  for (int k = 0; k < 1024; ++k) acc += zr[k] * wr[k];
  gx0[idx] = acc;
}

// ---------- persistent fused 2-layer LSTM, dataflow-synchronized ----------
// 192 blocks x 512 threads, 1 block/CU. Roles:
//   role0: layer0 recurrence (h0(t-1) -> h0(t))
//   role1: layer1 input-side (h0(t) -> pa(t), point-to-point to role2 partner)
//   role2: layer1 recurrence + pointwise + out (pa(t), h1(t-1) -> h1(t))
// vs previous version (two changes):
// 1. SYNC: the 2-hop master-wave grid barrier is replaced by per-ring
//    producer flags (monotone tags, 4-deep rings). Each role waits ONLY on
//    its own producers: one detect hop instead of arrive+broadcast+depart,
//    and roles are decoupled (no max-coupling of all 192 blocks).
//    Backpressure (slot t%4 overwrite safety) is proven by flag implication:
//      role0: paflag >= t-3  => role1 finished pa(t-4) => consumed h0(t-4)
//      role1: partner h1flag >= t-3 => role2 finished h1(t-4) => read pa(t-4)
//      self-rings: the A-wait (h flags >= t) implies all peers completed
//      step t-1, hence consumed everything <= t-2 (monotone).
//    All waits reference strictly-earlier publications => deadlock-free.
// 2. LDS PADDING: red/stage rows padded 16 -> 20 words (80 B stride, f32x4
//    still 16B-aligned; 20*lane mod 32 has period 8 => full bank spread).
//    red at stride 16 was an ~8-way ds_*_b128 conflict (the 1.19e8 counter).
__global__ __launch_bounds__(512, 2)
void lstm_persist(const float* __restrict__ Whh0, const float* __restrict__ Wih1,
                  const float* __restrict__ Whh1, const float* __restrict__ gx0,
                  const float* __restrict__ bih1, const float* __restrict__ bhh1,
                  u16* __restrict__ h0ring, u16* __restrict__ h1ring,
                  float* __restrict__ pabuf, float* __restrict__ out,
                  int* __restrict__ h0flag, int* __restrict__ paflag,
                  int* __restrict__ h1flag) {
  __shared__ __align__(16) u16 wlds[4][2048][8];       // 128 KiB (frag-major W)
  __shared__ __align__(16) float red[4][64][20];       // 20 KiB (padded rows)
  __shared__ __align__(16) float stage[128][20];       // 10 KiB (padded rows)

  const int bid = blockIdx.x;
  const int role = bid >> 6;
  const int cslice = bid & 63;
  const int cb = cslice * 16;        // h-col base
  const int tid = threadIdx.x;
  const int w = tid >> 6;            // wave 0..7
  const int lane = tid & 63;
  const int l15 = lane & 15;
  const int q = lane >> 4;
  const int Mg = w & 3;              // M-group: batches Mg*32..+32
  const int kh = w >> 2;             // K-half

  // ---- stage W slice fp32 -> bf16 -> LDS (once) ----
  {
    const float* Wsrc = (role == 0) ? Whh0 : (role == 1) ? Wih1 : Whh1;
    const int r = tid >> 3;          // 0..63: row within slice
    const int g = r >> 4, n = r & 15;
    const int k0 = (tid & 7) * 128;
    const float* src = Wsrc + (((size_t)(g * 1024 + cb + n)) << 10) + k0;
    for (int k = 0; k < 128; k += 4) {
      float4 v = *(const float4*)(src + k);
      ushort4 o;
      o.x = f2bf(v.x); o.y = f2bf(v.y); o.z = f2bf(v.z); o.w = f2bf(v.w);
      const int kk = k0 + k;
      *(ushort4*)&wlds[g][((kk >> 3) << 4) + n][kk & 7] = o;
    }
  }

  // ---- per-thread persistent state ----
  float c_st[2][4];
  #pragma unroll
  for (int mt = 0; mt < 2; ++mt)
    #pragma unroll
    for (int r = 0; r < 4; ++r) c_st[mt][r] = 0.f;

  float gx[2][4][4];                 // role0: gx0 base slice
  float b1[4];                       // role2: bias
  if (role == 0 && w < 4) {
    #pragma unroll
    for (int mt = 0; mt < 2; ++mt)
      #pragma unroll
      for (int g = 0; g < 4; ++g)
        #pragma unroll
        for (int r = 0; r < 4; ++r)
          gx[mt][g][r] = gx0[(size_t)(w * 32 + mt * 16 + q * 4 + r) * 4096 + g * 1024 + cb + l15];
  }
  if (role == 2 && w < 4) {
    #pragma unroll
    for (int g = 0; g < 4; ++g)
      b1[g] = bih1[g * 1024 + cb + l15] + bhh1[g * 1024 + cb + l15];
  }
  __syncthreads();

  const size_t HSLOT = (size_t)128 * 1024;   // elems per h ring slot

  for (int t = 0; t < T_SEQ; ++t) {
    const int sA = (t + 3) & 3;      // slot holding h(t-1)
    const int sW = t & 3;            // slot this step writes

    // ---- dataflow wait (wave 0 polls, then block-wide acquire) ----
    if (w == 0) {
      bool ok;
      if (role == 0) {
        // A: h0(t-1) (flag==t) from all 64 role0 blocks.
        // backpressure: role1 published pa(t-4) (flag>=t-3) => safe to
        // overwrite h0 slot sW (holds h0(t-4)). Trivially true for t<4.
        do {
          int fa = ld_agent(h0flag + (sA * 64 + lane) * FPAD);
          int fb = ld_agent(paflag + (sW * 64 + lane) * FPAD);
          ok = __all(fa >= t && fb >= t - 3);
          if (!ok) __builtin_amdgcn_s_sleep(1);
        } while (!ok);
      } else if (role == 1) {
        // A: h0(t) (flag==t+1). backpressure: partner role2 published
        // h1(t-4) => done reading pa(t-4) in pabuf slot sW.
        do {
          int fa = ld_agent(h0flag + (sW * 64 + lane) * FPAD);
          int fb = (lane == 0) ? ld_agent(h1flag + (sW * 64 + cslice) * FPAD)
                               : 0x7fffffff;
          ok = __all(fa >= t + 1 && fb >= t - 3);
          if (!ok) __builtin_amdgcn_s_sleep(1);
        } while (!ok);
      } else {
        // A: h1(t-1) (flag==t) from all 64 role2 blocks; pa(t) from partner.
        do {
          int fa = ld_agent(h1flag + (sA * 64 + lane) * FPAD);
          int fb = (lane == 0) ? ld_agent(paflag + (sW * 64 + cslice) * FPAD)
                               : 0x7fffffff;
          ok = __all(fa >= t && fb >= t + 1);
          if (!ok) __builtin_amdgcn_s_sleep(1);
        } while (!ok);
      }
      __builtin_amdgcn_fence(__ATOMIC_ACQUIRE, "agent");   // buffer_inv, no wbl2
    }
    __syncthreads();

    const u16* A = (role == 0) ? h0ring + (size_t)sA * HSLOT
                 : (role == 1) ? h0ring + (size_t)sW * HSLOT
                               : h1ring + (size_t)sA * HSLOT;

    const int kbase = kh * 512;
    const u16* Ap = A + (((size_t)(Mg * 32 + l15)) << 10) + kbase + q * 8;
    const int cellbase = ((kbase >> 3) + q) * 16 + l15;   // + kk*64

    f32x4 acc0[4] = {{0.f,0.f,0.f,0.f},{0.f,0.f,0.f,0.f},{0.f,0.f,0.f,0.f},{0.f,0.f,0.f,0.f}};
    f32x4 acc1[4] = {{0.f,0.f,0.f,0.f},{0.f,0.f,0.f,0.f},{0.f,0.f,0.f,0.f},{0.f,0.f,0.f,0.f}};

    #pragma unroll
    for (int kk = 0; kk < 16; ++kk) {
      bf16x8 a0 = *(const bf16x8*)(Ap + kk * 32);
      bf16x8 a1 = *(const bf16x8*)(Ap + (16 << 10) + kk * 32);
      #pragma unroll
      for (int g = 0; g < 4; ++g) {
        bf16x8 b = *(const bf16x8*)&wlds[g][cellbase + kk * 64][0];
        acc0[g] = __builtin_amdgcn_mfma_f32_16x16x32_bf16(a0, b, acc0[g], 0, 0, 0);
        acc1[g] = __builtin_amdgcn_mfma_f32_16x16x32_bf16(a1, b, acc1[g], 0, 0, 0);
      }
    }

    // role2: issue pabuf loads early (u64 atomics; compiler inserts the wait
    // before first use, the LDS reduction hides the latency)
    u64 pa64[16];
    const float* pr = pabuf + (size_t)sW * 524288 + (size_t)(cslice * 4 + w) * 2048;
    if (role == 2 && w < 4) {
      #pragma unroll
      for (int j = 0; j < 8; ++j) {
        pa64[j * 2]     = ld_agent((const u64*)pr + j * 128 + lane * 2);
        pa64[j * 2 + 1] = ld_agent((const u64*)pr + j * 128 + lane * 2 + 1);
      }
    }

    // ---- K-half reduction via LDS ----
    if (w >= 4) {
      #pragma unroll
      for (int g = 0; g < 4; ++g) *(f32x4*)&red[w - 4][lane][g * 4] = acc0[g];
    }
    __syncthreads();
    if (w < 4) {
      #pragma unroll
      for (int g = 0; g < 4; ++g) acc0[g] += *(const f32x4*)&red[w][lane][g * 4];
    }
    __syncthreads();
    if (w >= 4) {
      #pragma unroll
      for (int g = 0; g < 4; ++g) *(f32x4*)&red[w - 4][lane][g * 4] = acc1[g];
    }
    __syncthreads();
    if (w < 4) {
      #pragma unroll
      for (int g = 0; g < 4; ++g) acc1[g] += *(const f32x4*)&red[w][lane][g * 4];

      if (role == 1) {
        // coalesced full-K partials: u64 agent stores (compiler-tracked)
        float* pw = pabuf + (size_t)sW * 524288 + (size_t)(cslice * 4 + w) * 2048;
        #pragma unroll
        for (int g = 0; g < 4; ++g) {
          st_agent((u64*)pw + g * 128 + lane * 2,           pack2f(acc0[g][0], acc0[g][1]));
          st_agent((u64*)pw + g * 128 + lane * 2 + 1,       pack2f(acc0[g][2], acc0[g][3]));
          st_agent((u64*)pw + (4 + g) * 128 + lane * 2,     pack2f(acc1[g][0], acc1[g][1]));
          st_agent((u64*)pw + (4 + g) * 128 + lane * 2 + 1, pack2f(acc1[g][2], acc1[g][3]));
        }
      } else {
        #pragma unroll
        for (int mt = 0; mt < 2; ++mt) {
          #pragma unroll
          for (int r = 0; r < 4; ++r) {
            float xi, xf, xg, xo;
            f32x4* a = mt ? acc1 : acc0;
            if (role == 0) {
              xi = a[0][r] + gx[mt][0][r];
              xf = a[1][r] + gx[mt][1][r];
              xg = a[2][r] + gx[mt][2][r];
              xo = a[3][r] + gx[mt][3][r];
            } else {
              const int h2 = r >> 1, lo = r & 1;
              auto up = [&](int j) {
                u64 v = pa64[j * 2 + h2];
                return __uint_as_float(lo ? (unsigned)(v >> 32) : (unsigned)v);
              };
              xi = a[0][r] + up(mt * 4 + 0) + b1[0];
              xf = a[1][r] + up(mt * 4 + 1) + b1[1];
              xg = a[2][r] + up(mt * 4 + 2) + b1[2];
              xo = a[3][r] + up(mt * 4 + 3) + b1[3];
            }
            float i_ = sigm_(xi), f_ = sigm_(xf), g_ = tanh_(xg), o_ = sigm_(xo);
            float cn = f_ * c_st[mt][r] + i_ * g_;
            c_st[mt][r] = cn;
            float h = o_ * tanh_(cn);
            stage[w * 32 + mt * 16 + q * 4 + r][l15] = h;   // f32 h to LDS stage
          }
        }
      }
    }

    // ---- coalesced h / out stores (role0 & role2; all 512 threads) ----
    if (role != 1) {
      __syncthreads();                       // stage[] ready
      const int row = tid >> 2, qt = tid & 3;
      f32x4 v = *(const f32x4*)&stage[row][qt * 4];
      u64 pk = pack4bf(v);
      if (role == 0) {
        st_agent((u64*)(h0ring + (size_t)sW * HSLOT + ((size_t)row << 10) + cb) + qt, pk);
      } else {
        st_agent((u64*)(h1ring + (size_t)sW * HSLOT + ((size_t)row << 10) + cb) + qt, pk);
        // out has NO cross-block reader: plain cached store, kernel-end writeback
        *(f32x4*)(out + (size_t)row * ((size_t)T_SEQ * 1024) + (size_t)t * 1024 + cb + qt * 4) = v;
      }
    }

    // ---- publish: drain data stores, then monotone flag (one 64B line) ----
    __syncthreads();                 // per-wave vmcnt drain (atomic stores tracked)
    if (tid == 0) {
      if (role == 0)      st_agent(h0flag + (sW * 64 + cslice) * FPAD, t + 1);
      else if (role == 1) st_agent(paflag + (sW * 64 + cslice) * FPAD, t + 1);
      else                st_agent(h1flag + (sW * 64 + cslice) * FPAD, t + 1);
    }
  }
}

// ---------- launch ----------
extern "C" void kernel_launch(void* const* d_in, const int* in_sizes, int n_in,
                              void* d_out, int out_size, void* d_ws, size_t ws_size,
                              hipStream_t stream) {
  (void)in_sizes; (void)n_in; (void)out_size; (void)ws_size;
  const float* x    = (const float*)d_in[0];
  const float* fc_w = (const float*)d_in[1];
  const float* fc_b = (const float*)d_in[2];
  const float* Wih0 = (const float*)d_in[3];
  const float* Whh0 = (const float*)d_in[4];
  const float* bih0 = (const float*)d_in[5];
  const float* bhh0 = (const float*)d_in[6];
  const float* Wih1 = (const float*)d_in[7];
  const float* Whh1 = (const float*)d_in[8];
  const float* bih1 = (const float*)d_in[9];
  const float* bhh1 = (const float*)d_in[10];
  float* out = (float*)d_out;

  char* ws = (char*)d_ws;
  size_t off = 0;
  auto alloc = [&](size_t bytes) -> void* {
    void* p = ws + off;
    off += (bytes + 255) & ~(size_t)255;
    return p;
  };
  float* z      = (float*)alloc((size_t)128 * 1024 * 4);
  float* gx0    = (float*)alloc((size_t)128 * 4096 * 4);
  u16*   h0ring = (u16*)alloc((size_t)RSLOT * 128 * 1024 * 2);
  u16*   h1ring = (u16*)alloc((size_t)RSLOT * 128 * 1024 * 2);
  float* pabuf  = (float*)alloc((size_t)RSLOT * 524288 * 4);
  int*   h0flag = (int*)alloc((size_t)RSLOT * 64 * FPAD * 4);
  int*   paflag = (int*)alloc((size_t)RSLOT * 64 * FPAD * 4);
  int*   h1flag = (int*)alloc((size_t)RSLOT * 64 * FPAD * 4);

  hipMemsetAsync(h0ring, 0, (size_t)RSLOT * 128 * 1024 * 2, stream);
  hipMemsetAsync(h1ring, 0, (size_t)RSLOT * 128 * 1024 * 2, stream);
  hipMemsetAsync(h0flag, 0, (size_t)RSLOT * 64 * FPAD * 4, stream);
  hipMemsetAsync(paflag, 0, (size_t)RSLOT * 64 * FPAD * 4, stream);
  hipMemsetAsync(h1flag, 0, (size_t)RSLOT * 64 * FPAD * 4, stream);

  fc_kernel<<<512, 256, 0, stream>>>(x, fc_w, fc_b, z);
  gx0_kernel<<<2048, 256, 0, stream>>>(z, Wih0, bih0, bhh0, gx0);

  lstm_persist<<<NBLK, 512, 0, stream>>>(Whh0, Wih1, Whh1, gx0, bih1, bhh1,
                                         h0ring, h1ring, pabuf, out,
                                         h0flag, paflag, h1flag);
}